// Round 5
// baseline (319.831 us; speedup 1.0000x reference)
//
#include <hip/hip_runtime.h>

#define NN 100000
#define NE 1600000
#define CAP 64
#define NCLUST 1024
#define OUT_POOLED_POS 65536
#define OUT_POS        67584
#define OUT_BATCH      267584

// ---------------------------------------------------------------------------
// K1: bucket-CSR fill. slot = wp[col]++ ; csr[col*64 + slot] = row.
// Nontemporal stores: scattered 4B stores would RFO-thrash the 4MB per-XCD
// L2 (csr = 25.6MB random); NT = no-allocate write-through w/ byte enables.
// ---------------------------------------------------------------------------
__global__ __launch_bounds__(256) void fill_kernel(const int* __restrict__ ei,
                                                   int* __restrict__ wp,
                                                   int* __restrict__ csr)
{
    int t = blockIdx.x * 256 + threadIdx.x;
    int e0 = t * 4;
    if (e0 + 3 < NE) {
        int4 r = *(const int4*)(ei + e0);
        int4 c = *(const int4*)(ei + NE + e0);
        int s;
        s = atomicAdd(&wp[c.x], 1);
        if (s < CAP) __builtin_nontemporal_store(r.x, csr + (size_t)c.x * CAP + s);
        s = atomicAdd(&wp[c.y], 1);
        if (s < CAP) __builtin_nontemporal_store(r.y, csr + (size_t)c.y * CAP + s);
        s = atomicAdd(&wp[c.z], 1);
        if (s < CAP) __builtin_nontemporal_store(r.z, csr + (size_t)c.z * CAP + s);
        s = atomicAdd(&wp[c.w], 1);
        if (s < CAP) __builtin_nontemporal_store(r.w, csr + (size_t)c.w * CAP + s);
    } else {
        for (int e = e0; e < NE; ++e) {
            int c = ei[NE + e];
            int s = atomicAdd(&wp[c], 1);
            if (s < CAP) __builtin_nontemporal_store(ei[e], csr + (size_t)c * CAP + s);
        }
    }
}

// ---------------------------------------------------------------------------
// K2: fused gather + mean + linear + relu + voxel max-pool + pos epilogue.
// Single pass: 1563 blocks x 16 waves x 4 nodes. Waves independent after
// W staging. Edge loop is a DEPTH-2 split pipeline: csr 2 ahead, pos/x 1
// ahead -> each hop of the 2-hop chain gets a full iteration to return.
// lane = q*16 + g*8 + s : q=node, g=edge half, s=ch/4.
// Epilogue: atomicMax elided when a (stale-safe) load shows h <= current.
// ---------------------------------------------------------------------------
__global__ __launch_bounds__(1024, 8) void fused_kernel(
    const float4* __restrict__ x4,    // [NN*8]
    const float2* __restrict__ pos2,  // [NN]
    const int* __restrict__ batch,
    const float4* __restrict__ W4,    // W[64][128] as float4 [64*32]
    const float* __restrict__ bv,
    const int* __restrict__ wp,
    const int* __restrict__ csr,
    float* __restrict__ out,
    float* __restrict__ pos_sum,
    float* __restrict__ node_cnt)
{
    __shared__ float4 Wt4[32 * 64];      // [k4][oc]
    __shared__ float  bs[64];
    __shared__ float4 prop4[16][4][32];  // [wave][q][k4]

    {
        int oc0 = threadIdx.x & 63;
        int k0  = threadIdx.x >> 6;      // 0..15
        Wt4[k0 * 64 + oc0]        = W4[oc0 * 32 + k0];
        Wt4[(k0 + 16) * 64 + oc0] = W4[oc0 * 32 + k0 + 16];
        if (threadIdx.x < 64) bs[threadIdx.x] = bv[threadIdx.x];
    }
    __syncthreads();

    const int wid  = threadIdx.x >> 6;
    const int lane = threadIdx.x & 63;
    const int q  = lane >> 4;
    const int g  = (lane >> 3) & 1;
    const int s  = lane & 7;
    const int oc = lane;

    int wg = blockIdx.x * 16 + wid;
    if (wg * 4 >= NN) return;            // no barriers after this point

    int n = wg * 4 + q;
    bool act = (n < NN);
    int nn = act ? n : 0;

    int cnt = wp[nn];
    int deg = act ? min(cnt, CAP) : 0;
    float4 vi = x4[(size_t)nn * 8 + s];
    float2 pi = pos2[nn];
    const int* bk = csr + (size_t)nn * CAP;

    // wave-uniform max degree (q lives in lane bits 4..5)
    int md = deg;
    md = max(md, __shfl_xor(md, 16));
    md = max(md, __shfl_xor(md, 32));

    float a0x=0,a0y=0,a0z=0,a0w=0;
    float a1x=0,a1y=0,a1z=0,a1w=0;
    float a2x=0,a2y=0,a2z=0,a2w=0;

    // depth-2 pipeline prologue
    int k0i = g;
    bool p0 = (k0i < deg);
    int j0 = p0 ? bk[k0i] : nn;
    float m0 = p0 ? 1.0f : 0.0f;
    float2 pj0 = pos2[j0];
    float4 vj0 = x4[(size_t)j0 * 8 + s];

    int k1 = g + 2;
    bool p1 = (k1 < deg);
    int j1 = p1 ? bk[k1] : nn;
    float m1 = p1 ? 1.0f : 0.0f;

    int iters = (md + 1) >> 1;
    for (int it = 0; it < iters; ++it) {
        // stage A: csr 2 ahead
        int k2 = k1 + 2;
        bool p2 = (k2 < deg);
        int j2 = p2 ? bk[k2] : nn;
        float m2 = p2 ? 1.0f : 0.0f;
        // stage B: pos/x 1 ahead (j1 returned during previous iteration)
        float2 pjn = pos2[j1];
        float4 vjn = x4[(size_t)j1 * 8 + s];

        // compute current edge (pj0, vj0, m0)
        float dx = pi.x - pj0.x, dy = pi.y - pj0.y;
        float inv = m0 * __builtin_amdgcn_rcpf(dx * dx + dy * dy + 0.01f);
        float wx = dx * inv, wy = dy * inv;
        float vdx = vi.x - vj0.x, vdy = vi.y - vj0.y;
        float vdz = vi.z - vj0.z, vdw = vi.w - vj0.w;
        a0x += vdx * wx; a0y += vdy * wx; a0z += vdz * wx; a0w += vdw * wx;
        a1x += vdx * wy; a1y += vdy * wy; a1z += vdz * wy; a1w += vdw * wy;
        a2x += vj0.x * m0; a2y += vj0.y * m0; a2z += vj0.z * m0; a2w += vj0.w * m0;

        // rotate
        pj0 = pjn; vj0 = vjn; m0 = m1;
        j1 = j2; m1 = m2; k1 = k2;
    }

    // combine edge halves (partner differs in bit 3 = g)
    a0x += __shfl_xor(a0x, 8); a0y += __shfl_xor(a0y, 8);
    a0z += __shfl_xor(a0z, 8); a0w += __shfl_xor(a0w, 8);
    a1x += __shfl_xor(a1x, 8); a1y += __shfl_xor(a1y, 8);
    a1z += __shfl_xor(a1z, 8); a1w += __shfl_xor(a1w, 8);
    a2x += __shfl_xor(a2x, 8); a2y += __shfl_xor(a2y, 8);
    a2z += __shfl_xor(a2z, 8); a2w += __shfl_xor(a2w, 8);

    float invd = 1.0f / fmaxf((float)cnt, 1.0f);
    if (g == 0) {
        prop4[wid][q][s]      = make_float4(a0x*invd, a0y*invd, a0z*invd, a0w*invd);
        prop4[wid][q][8 + s]  = make_float4(a1x*invd, a1y*invd, a1z*invd, a1w*invd);
        prop4[wid][q][16 + s] = make_float4(a2x*invd, a2y*invd, a2z*invd, a2w*invd);
        prop4[wid][q][24 + s] = vi;
    }
    // same-wave LDS RAW fence (prop is wave-private; no barrier needed)
    asm volatile("s_waitcnt lgkmcnt(0)" ::: "memory");

    // matvec: lane = oc, 4 nodes per W-read
    float bb = bs[oc];
    float acc0 = bb, acc1 = bb, acc2 = bb, acc3 = bb;
    #pragma unroll 8
    for (int k4 = 0; k4 < 32; ++k4) {
        float4 w  = Wt4[k4 * 64 + oc];
        float4 pp0 = prop4[wid][0][k4];
        float4 pp1 = prop4[wid][1][k4];
        float4 pp2 = prop4[wid][2][k4];
        float4 pp3 = prop4[wid][3][k4];
        acc0 += w.x*pp0.x + w.y*pp0.y + w.z*pp0.z + w.w*pp0.w;
        acc1 += w.x*pp1.x + w.y*pp1.y + w.z*pp1.z + w.w*pp1.w;
        acc2 += w.x*pp2.x + w.y*pp2.y + w.z*pp2.z + w.w*pp2.w;
        acc3 += w.x*pp3.x + w.y*pp3.y + w.z*pp3.z + w.w*pp3.w;
    }

    float accq[4] = {acc0, acc1, acc2, acc3};
    #pragma unroll
    for (int qq = 0; qq < 4; ++qq) {
        int n2 = wg * 4 + qq;
        if (n2 < NN) {
            float h = fmaxf(accq[qq], 0.0f);
            float2 pp = pos2[n2];
            int b = batch[n2];
            int vx = min(max((int)floorf(pp.x * 16.0f), 0), 15);
            int vy = min(max((int)floorf(pp.y * 16.0f), 0), 15);
            int cl = b * 256 + vy * 16 + vx;
            unsigned int* tgt = (unsigned int*)(out + (size_t)cl * 64 + oc);
            // monotonic-from-zero: any read value is a valid lower bound of
            // the final max (h >= 0, so uint compare == float compare)
            unsigned int prev = *tgt;
            unsigned int cur  = __float_as_uint(h);
            if (cur > prev) atomicMax(tgt, cur);
            if (oc == qq) {
                *(float2*)(out + OUT_POS + 2 * (size_t)n2) = pp;
                out[OUT_BATCH + n2] = (float)b;
                atomicAdd(pos_sum + 2 * cl,     pp.x);
                atomicAdd(pos_sum + 2 * cl + 1, pp.y);
                atomicAdd(node_cnt + cl, 1.0f);
            }
        }
    }
}

// ---------------------------------------------------------------------------
// K3: finalize pooled positions.
// ---------------------------------------------------------------------------
__global__ void finalize_kernel(const float* __restrict__ pos_sum,
                                const float* __restrict__ node_cnt,
                                float* __restrict__ out_pooled_pos)
{
    int c = blockIdx.x * blockDim.x + threadIdx.x;
    if (c >= NCLUST) return;
    float inv = 1.0f / fmaxf(node_cnt[c], 1.0f);
    out_pooled_pos[2 * c]     = pos_sum[2 * c] * inv;
    out_pooled_pos[2 * c + 1] = pos_sum[2 * c + 1] * inv;
}

extern "C" void kernel_launch(void* const* d_in, const int* in_sizes, int n_in,
                              void* d_out, int out_size, void* d_ws, size_t ws_size,
                              hipStream_t stream)
{
    const float* x     = (const float*)d_in[0];
    const int*   ei    = (const int*)d_in[1];
    const float* pos   = (const float*)d_in[2];
    const int*   batch = (const int*)d_in[3];
    const float* W     = (const float*)d_in[4];
    const float* bvec  = (const float*)d_in[5];
    float* out = (float*)d_out;

    // ws layout (4B): wp[NN] | csr[NN*CAP] | pos_sum[2048] | node_cnt[1024]
    int* wp  = (int*)d_ws;
    int* csr = wp + NN;
    float* pos_sum  = (float*)(csr + (size_t)NN * CAP);
    float* node_cnt = pos_sum + 2 * NCLUST;

    hipMemsetAsync(wp, 0, NN * sizeof(int), stream);
    hipMemsetAsync(pos_sum, 0, 3 * NCLUST * sizeof(float), stream);
    hipMemsetAsync(d_out, 0, (size_t)NCLUST * 64 * sizeof(float), stream);

    fill_kernel<<<(NE / 4 + 255) / 256, 256, 0, stream>>>(ei, wp, csr);

    // one node-group (4 nodes) per wave: ceil(100000 / (16*4)) = 1563 blocks
    fused_kernel<<<1563, 1024, 0, stream>>>(
        (const float4*)x, (const float2*)pos, batch,
        (const float4*)W, bvec, wp, csr, out, pos_sum, node_cnt);

    finalize_kernel<<<(NCLUST + 255) / 256, 256, 0, stream>>>(
        pos_sum, node_cnt, out + NCLUST * 64);
}

// Round 6
// 276.547 us; speedup vs baseline: 1.1565x; 1.1565x over previous
//
#include <hip/hip_runtime.h>
#include <hip/hip_fp16.h>

#define NN 100000
#define NE 1600000
#define NCLUST 1024
#define OUT_POOLED_POS 65536
#define OUT_POS        67584
#define OUT_BATCH      267584

// ---------------------------------------------------------------------------
// K1: bucket-CSR fill with PRECOMPUTED edge weights.
// entry = uint2{ j, fp16x2(wx, wy) } at csr64[col*cap + slot].
// One 8B scattered store per edge (same cache-line count as 4B).
// pos (800KB) is L2-resident -> the two pos gathers are cheap.
// ---------------------------------------------------------------------------
__global__ __launch_bounds__(256) void fill_kernel(const int* __restrict__ ei,
                                                   const float2* __restrict__ pos2,
                                                   int* __restrict__ wp,
                                                   uint2* __restrict__ csr64,
                                                   int cap)
{
    int t = blockIdx.x * 256 + threadIdx.x;
    int e0 = t * 4;
    if (e0 + 3 < NE) {
        int4 r = *(const int4*)(ei + e0);
        int4 c = *(const int4*)(ei + NE + e0);
        int rr[4] = {r.x, r.y, r.z, r.w};
        int cc[4] = {c.x, c.y, c.z, c.w};
        #pragma unroll
        for (int u = 0; u < 4; ++u) {
            int row = rr[u], col = cc[u];
            float2 pi = pos2[col], pj = pos2[row];
            float dx = pi.x - pj.x, dy = pi.y - pj.y;
            float inv = __builtin_amdgcn_rcpf(dx * dx + dy * dy + 0.01f);
            __half2 h2 = __floats2half2_rn(dx * inv, dy * inv);
            unsigned int wbits = *reinterpret_cast<unsigned int*>(&h2);
            int s = atomicAdd(&wp[col], 1);
            if (s < cap) csr64[(size_t)col * cap + s] = make_uint2((unsigned)row, wbits);
        }
    } else {
        for (int e = e0; e < NE; ++e) {
            int row = ei[e], col = ei[NE + e];
            float2 pi = pos2[col], pj = pos2[row];
            float dx = pi.x - pj.x, dy = pi.y - pj.y;
            float inv = __builtin_amdgcn_rcpf(dx * dx + dy * dy + 0.01f);
            __half2 h2 = __floats2half2_rn(dx * inv, dy * inv);
            unsigned int wbits = *reinterpret_cast<unsigned int*>(&h2);
            int s = atomicAdd(&wp[col], 1);
            if (s < cap) csr64[(size_t)col * cap + s] = make_uint2((unsigned)row, wbits);
        }
    }
}

// ---------------------------------------------------------------------------
// K2: fused gather + mean + linear + relu + voxel max-pool + pos epilogue.
// 512 blocks x 16 waves, per-wave grid-stride (W staged once per block,
// amortized over ~196 nodes). Waves independent: prop is wave-private LDS,
// ordered by s_waitcnt lgkmcnt(0) fences (no barriers in loop).
// Edge loop: contiguous csr64 read (depth-2) -> one random x4[j] (depth-1).
// w comes packed from the CSR entry -> per-edge chain is 1 hop.
// lane = q*16 + g*8 + s : q=node(4/wave), g=edge half, s=ch/4.
// ---------------------------------------------------------------------------
__global__ __launch_bounds__(1024, 8) void fused_kernel(
    const float4* __restrict__ x4,    // [NN*8]
    const float2* __restrict__ pos2,  // [NN]
    const int* __restrict__ batch,
    const float4* __restrict__ W4,    // W[64][128] as float4 [64*32]
    const float* __restrict__ bv,
    const int* __restrict__ wp,
    const uint2* __restrict__ csr64,
    int cap,
    float* __restrict__ out,
    float* __restrict__ pos_sum,
    float* __restrict__ node_cnt)
{
    __shared__ float4 Wt4[32 * 64];      // [k4][oc]
    __shared__ float  bs[64];
    __shared__ float4 prop4[16][4][32];  // [wave][q][k4]

    {
        int oc0 = threadIdx.x & 63;
        int k0  = threadIdx.x >> 6;      // 0..15
        Wt4[k0 * 64 + oc0]        = W4[oc0 * 32 + k0];
        Wt4[(k0 + 16) * 64 + oc0] = W4[oc0 * 32 + k0 + 16];
        if (threadIdx.x < 64) bs[threadIdx.x] = bv[threadIdx.x];
    }
    __syncthreads();

    const int wid  = threadIdx.x >> 6;
    const int lane = threadIdx.x & 63;
    const int q  = lane >> 4;
    const int g  = (lane >> 3) & 1;
    const int s  = lane & 7;
    const int oc = lane;
    const int nwaves = gridDim.x * 16;

    for (int wg = blockIdx.x * 16 + wid; wg * 4 < NN; wg += nwaves) {
        int n = wg * 4 + q;
        bool act = (n < NN);
        int nn = act ? n : 0;

        int cnt = wp[nn];
        int deg = act ? min(cnt, cap) : 0;
        float4 vi = x4[(size_t)nn * 8 + s];
        const uint2* bk = csr64 + (size_t)nn * cap;

        // wave-uniform max degree (q lives in lane bits 4..5)
        int md = deg;
        md = max(md, __shfl_xor(md, 16));
        md = max(md, __shfl_xor(md, 32));

        float a0x=0,a0y=0,a0z=0,a0w=0;
        float a1x=0,a1y=0,a1z=0,a1w=0;
        float a2x=0,a2y=0,a2z=0,a2w=0;

        // pipeline prologue: entry for k (current) and k+2 (next)
        int k0i = g;
        bool p0 = (k0i < deg);
        uint2 e0 = p0 ? bk[k0i] : make_uint2((unsigned)nn, 0u);
        float m0 = p0 ? 1.0f : 0.0f;
        float4 vj0 = x4[(size_t)e0.x * 8 + s];

        int k1 = g + 2;
        bool p1 = (k1 < deg);
        uint2 e1 = p1 ? bk[k1] : make_uint2((unsigned)nn, 0u);
        float m1 = p1 ? 1.0f : 0.0f;

        int iters = (md + 1) >> 1;
        for (int it = 0; it < iters; ++it) {
            // csr entry 2 ahead (contiguous)
            int k2 = k1 + 2;
            bool p2 = (k2 < deg);
            uint2 e2 = p2 ? bk[k2] : make_uint2((unsigned)nn, 0u);
            float m2 = p2 ? 1.0f : 0.0f;
            // x row 1 ahead (random; index from csr entry loaded last iter)
            float4 vjn = x4[(size_t)e1.x * 8 + s];

            // compute current edge (e0, vj0, m0); dummy entries have w=0
            unsigned int wb = e0.y;
            __half2 h2 = *reinterpret_cast<__half2*>(&wb);
            float2 wf = __half22float2(h2);
            float wx = wf.x, wy = wf.y;
            float vdx = vi.x - vj0.x, vdy = vi.y - vj0.y;
            float vdz = vi.z - vj0.z, vdw = vi.w - vj0.w;
            a0x += vdx * wx; a0y += vdy * wx; a0z += vdz * wx; a0w += vdw * wx;
            a1x += vdx * wy; a1y += vdy * wy; a1z += vdz * wy; a1w += vdw * wy;
            a2x += vj0.x * m0; a2y += vj0.y * m0; a2z += vj0.z * m0; a2w += vj0.w * m0;

            // rotate
            e0 = e1; m0 = m1; vj0 = vjn;
            e1 = e2; m1 = m2; k1 = k2;
        }

        // combine edge halves (partner differs in bit 3 = g)
        a0x += __shfl_xor(a0x, 8); a0y += __shfl_xor(a0y, 8);
        a0z += __shfl_xor(a0z, 8); a0w += __shfl_xor(a0w, 8);
        a1x += __shfl_xor(a1x, 8); a1y += __shfl_xor(a1y, 8);
        a1z += __shfl_xor(a1z, 8); a1w += __shfl_xor(a1w, 8);
        a2x += __shfl_xor(a2x, 8); a2y += __shfl_xor(a2y, 8);
        a2z += __shfl_xor(a2z, 8); a2w += __shfl_xor(a2w, 8);

        float invd = 1.0f / fmaxf((float)cnt, 1.0f);
        if (g == 0) {
            prop4[wid][q][s]      = make_float4(a0x*invd, a0y*invd, a0z*invd, a0w*invd);
            prop4[wid][q][8 + s]  = make_float4(a1x*invd, a1y*invd, a1z*invd, a1w*invd);
            prop4[wid][q][16 + s] = make_float4(a2x*invd, a2y*invd, a2z*invd, a2w*invd);
            prop4[wid][q][24 + s] = vi;
        }
        // same-wave LDS RAW fence (prop is wave-private; no barrier needed)
        asm volatile("s_waitcnt lgkmcnt(0)" ::: "memory");

        // matvec: lane = oc, 4 nodes per W-read
        float bb = bs[oc];
        float acc0 = bb, acc1 = bb, acc2 = bb, acc3 = bb;
        #pragma unroll 8
        for (int k4 = 0; k4 < 32; ++k4) {
            float4 w  = Wt4[k4 * 64 + oc];
            float4 pp0 = prop4[wid][0][k4];
            float4 pp1 = prop4[wid][1][k4];
            float4 pp2 = prop4[wid][2][k4];
            float4 pp3 = prop4[wid][3][k4];
            acc0 += w.x*pp0.x + w.y*pp0.y + w.z*pp0.z + w.w*pp0.w;
            acc1 += w.x*pp1.x + w.y*pp1.y + w.z*pp1.z + w.w*pp1.w;
            acc2 += w.x*pp2.x + w.y*pp2.y + w.z*pp2.z + w.w*pp2.w;
            acc3 += w.x*pp3.x + w.y*pp3.y + w.z*pp3.z + w.w*pp3.w;
        }

        float accq[4] = {acc0, acc1, acc2, acc3};
        #pragma unroll
        for (int qq = 0; qq < 4; ++qq) {
            int n2 = wg * 4 + qq;
            if (n2 < NN) {
                float h = fmaxf(accq[qq], 0.0f);
                float2 pp = pos2[n2];
                int b = batch[n2];
                int vx = min(max((int)floorf(pp.x * 16.0f), 0), 15);
                int vy = min(max((int)floorf(pp.y * 16.0f), 0), 15);
                int cl = b * 256 + vy * 16 + vx;
                unsigned int* tgt = (unsigned int*)(out + (size_t)cl * 64 + oc);
                // monotonic-from-zero: stale read is a valid lower bound
                unsigned int prev = *tgt;
                unsigned int cur  = __float_as_uint(h);
                if (cur > prev) atomicMax(tgt, cur);
                if (oc == qq) {
                    *(float2*)(out + OUT_POS + 2 * (size_t)n2) = pp;
                    out[OUT_BATCH + n2] = (float)b;
                    atomicAdd(pos_sum + 2 * cl,     pp.x);
                    atomicAdd(pos_sum + 2 * cl + 1, pp.y);
                    atomicAdd(node_cnt + cl, 1.0f);
                }
            }
        }
        // WAR fence before next iteration overwrites prop
        asm volatile("s_waitcnt lgkmcnt(0)" ::: "memory");
    }
}

// ---------------------------------------------------------------------------
// K3: finalize pooled positions.
// ---------------------------------------------------------------------------
__global__ void finalize_kernel(const float* __restrict__ pos_sum,
                                const float* __restrict__ node_cnt,
                                float* __restrict__ out_pooled_pos)
{
    int c = blockIdx.x * blockDim.x + threadIdx.x;
    if (c >= NCLUST) return;
    float inv = 1.0f / fmaxf(node_cnt[c], 1.0f);
    out_pooled_pos[2 * c]     = pos_sum[2 * c] * inv;
    out_pooled_pos[2 * c + 1] = pos_sum[2 * c + 1] * inv;
}

extern "C" void kernel_launch(void* const* d_in, const int* in_sizes, int n_in,
                              void* d_out, int out_size, void* d_ws, size_t ws_size,
                              hipStream_t stream)
{
    const float* x     = (const float*)d_in[0];
    const int*   ei    = (const int*)d_in[1];
    const float* pos   = (const float*)d_in[2];
    const int*   batch = (const int*)d_in[3];
    const float* W     = (const float*)d_in[4];
    const float* bvec  = (const float*)d_in[5];
    float* out = (float*)d_out;

    // cap: 48 entries (P(Poisson(16) > 48) * 1e5 ~ 1e-5); shrink if ws tight
    size_t fixed = (size_t)NN * sizeof(int) + 3 * NCLUST * sizeof(float);
    int cap = 48;
    if (ws_size < fixed + (size_t)NN * cap * 8) {
        cap = (int)((ws_size - fixed) / ((size_t)NN * 8));
        if (cap > 48) cap = 48;
    }

    // ws layout (bytes): wp[NN] ints | csr64[NN*cap] uint2 | pos_sum | node_cnt
    int* wp = (int*)d_ws;
    uint2* csr64 = (uint2*)(wp + NN);
    float* pos_sum  = (float*)(csr64 + (size_t)NN * cap);
    float* node_cnt = pos_sum + 2 * NCLUST;

    hipMemsetAsync(wp, 0, NN * sizeof(int), stream);
    hipMemsetAsync(pos_sum, 0, 3 * NCLUST * sizeof(float), stream);
    hipMemsetAsync(d_out, 0, (size_t)NCLUST * 64 * sizeof(float), stream);

    fill_kernel<<<(NE / 4 + 255) / 256, 256, 0, stream>>>(
        ei, (const float2*)pos, wp, csr64, cap);

    fused_kernel<<<512, 1024, 0, stream>>>(
        (const float4*)x, (const float2*)pos, batch,
        (const float4*)W, bvec, wp, csr64, cap, out, pos_sum, node_cnt);

    finalize_kernel<<<(NCLUST + 255) / 256, 256, 0, stream>>>(
        pos_sum, node_cnt, out + NCLUST * 64);
}

// Round 7
// 262.015 us; speedup vs baseline: 1.2207x; 1.0555x over previous
//
#include <hip/hip_runtime.h>
#include <hip/hip_fp16.h>

#define NN 100000
#define NE 1600000
#define NCLUST 1024
#define OUT_POOLED_POS 65536
#define OUT_POS        67584
#define OUT_BATCH      267584

static __device__ __forceinline__ float2 h2f(unsigned int u)
{
    __half2 h = *reinterpret_cast<__half2*>(&u);
    return __half22float2(h);
}

// ---------------------------------------------------------------------------
// K0: x -> fp16 (gather copy). xh2[n*8+s] = half4 of channels 4s..4s+3.
// ---------------------------------------------------------------------------
__global__ __launch_bounds__(256) void cvt_kernel(const float4* __restrict__ x4,
                                                  uint2* __restrict__ xh2)
{
    int t = blockIdx.x * 256 + threadIdx.x;
    if (t >= NN * 8) return;
    float4 v = x4[t];
    __half2 lo = __floats2half2_rn(v.x, v.y);
    __half2 hi = __floats2half2_rn(v.z, v.w);
    uint2 o;
    o.x = *reinterpret_cast<unsigned int*>(&lo);
    o.y = *reinterpret_cast<unsigned int*>(&hi);
    xh2[t] = o;
}

// ---------------------------------------------------------------------------
// K1: bucket-CSR fill with precomputed edge weights.
// entry = uint2{ j, fp16x2(wx, wy) } at csr64[col*cap + slot].
// ---------------------------------------------------------------------------
__global__ __launch_bounds__(256) void fill_kernel(const int* __restrict__ ei,
                                                   const float2* __restrict__ pos2,
                                                   int* __restrict__ wp,
                                                   uint2* __restrict__ csr64,
                                                   int cap)
{
    int t = blockIdx.x * 256 + threadIdx.x;
    int e0 = t * 4;
    if (e0 + 3 < NE) {
        int4 r = *(const int4*)(ei + e0);
        int4 c = *(const int4*)(ei + NE + e0);
        int rr[4] = {r.x, r.y, r.z, r.w};
        int cc[4] = {c.x, c.y, c.z, c.w};
        #pragma unroll
        for (int u = 0; u < 4; ++u) {
            int row = rr[u], col = cc[u];
            float2 pi = pos2[col], pj = pos2[row];
            float dx = pi.x - pj.x, dy = pi.y - pj.y;
            float inv = __builtin_amdgcn_rcpf(dx * dx + dy * dy + 0.01f);
            __half2 h2 = __floats2half2_rn(dx * inv, dy * inv);
            unsigned int wbits = *reinterpret_cast<unsigned int*>(&h2);
            int s = atomicAdd(&wp[col], 1);
            if (s < cap) csr64[(size_t)col * cap + s] = make_uint2((unsigned)row, wbits);
        }
    } else {
        for (int e = e0; e < NE; ++e) {
            int row = ei[e], col = ei[NE + e];
            float2 pi = pos2[col], pj = pos2[row];
            float dx = pi.x - pj.x, dy = pi.y - pj.y;
            float inv = __builtin_amdgcn_rcpf(dx * dx + dy * dy + 0.01f);
            __half2 h2 = __floats2half2_rn(dx * inv, dy * inv);
            unsigned int wbits = *reinterpret_cast<unsigned int*>(&h2);
            int s = atomicAdd(&wp[col], 1);
            if (s < cap) csr64[(size_t)col * cap + s] = make_uint2((unsigned)row, wbits);
        }
    }
}

// ---------------------------------------------------------------------------
// K2: fused gather + mean + linear + relu + voxel max-pool + pos epilogue.
// 512 blocks x 16 waves, per-wave grid-stride. Waves independent in loop.
// Edge loop: BATCH-4 pipeline -- per step, 4 CSR entries (contiguous) are
// loaded and 4 fp16 x-rows issued, while the previous batch computes.
// 4 outstanding random gathers/lane (vs 1 before) = 4x MLP.
// lane = q*16 + g*8 + s : q=node(4/wave), g=edge half, s=ch/4.
// ---------------------------------------------------------------------------
__global__ __launch_bounds__(1024, 8) void fused_kernel(
    const float4* __restrict__ x4,    // [NN*8] f32
    const uint2*  __restrict__ xh2,   // [NN*8] fp16
    const float2* __restrict__ pos2,
    const int* __restrict__ batch,
    const float4* __restrict__ W4,    // W[64][128] as float4
    const float* __restrict__ bv,
    const int* __restrict__ wp,
    const uint2* __restrict__ csr64,
    int cap,
    float* __restrict__ out,
    float* __restrict__ pos_sum,
    float* __restrict__ node_cnt)
{
    __shared__ float4 Wt4[32 * 64];      // [k4][oc]
    __shared__ float  bs[64];
    __shared__ float4 prop4[16][4][32];  // [wave][q][k4]

    {
        int oc0 = threadIdx.x & 63;
        int k0  = threadIdx.x >> 6;
        Wt4[k0 * 64 + oc0]        = W4[oc0 * 32 + k0];
        Wt4[(k0 + 16) * 64 + oc0] = W4[oc0 * 32 + k0 + 16];
        if (threadIdx.x < 64) bs[threadIdx.x] = bv[threadIdx.x];
    }
    __syncthreads();

    const int wid  = threadIdx.x >> 6;
    const int lane = threadIdx.x & 63;
    const int q  = lane >> 4;
    const int g  = (lane >> 3) & 1;
    const int s  = lane & 7;
    const int oc = lane;
    const int nwaves = gridDim.x * 16;

    for (int wg = blockIdx.x * 16 + wid; wg * 4 < NN; wg += nwaves) {
        int n = wg * 4 + q;
        bool act = (n < NN);
        int nn = act ? n : 0;

        int cnt = wp[nn];
        int deg = act ? min(cnt, cap) : 0;
        float4 vi = x4[(size_t)nn * 8 + s];
        const uint2* bk = csr64 + (size_t)nn * cap;

        // wave-uniform max degree (q lives in lane bits 4..5)
        int md = deg;
        md = max(md, __shfl_xor(md, 16));
        md = max(md, __shfl_xor(md, 32));

        float a0x=0,a0y=0,a0z=0,a0w=0;
        float a1x=0,a1y=0,a1z=0,a1w=0;
        float a2x=0,a2y=0,a2z=0,a2w=0;

        // batch-4 prologue: entries + x issues for batch 0 (edges kb+2u, u<4)
        int kb = g;
        uint2 E0 = (kb     < deg) ? bk[kb]     : make_uint2((unsigned)nn, 0u);
        uint2 E1 = (kb + 2 < deg) ? bk[kb + 2] : make_uint2((unsigned)nn, 0u);
        uint2 E2 = (kb + 4 < deg) ? bk[kb + 4] : make_uint2((unsigned)nn, 0u);
        uint2 E3 = (kb + 6 < deg) ? bk[kb + 6] : make_uint2((unsigned)nn, 0u);
        uint2 X0 = xh2[(size_t)E0.x * 8 + s];
        uint2 X1 = xh2[(size_t)E1.x * 8 + s];
        uint2 X2 = xh2[(size_t)E2.x * 8 + s];
        uint2 X3 = xh2[(size_t)E3.x * 8 + s];
        unsigned int B0 = E0.y, B1 = E1.y, B2 = E2.y, B3 = E3.y;

        int iters = (md + 7) >> 3;           // wave-uniform
        for (int it = 0; it < iters; ++it) {
            int nb = kb + 8;
            // next-batch entries (contiguous, L2-hot)
            uint2 F0 = (nb     < deg) ? bk[nb]     : make_uint2((unsigned)nn, 0u);
            uint2 F1 = (nb + 2 < deg) ? bk[nb + 2] : make_uint2((unsigned)nn, 0u);
            uint2 F2 = (nb + 4 < deg) ? bk[nb + 4] : make_uint2((unsigned)nn, 0u);
            uint2 F3 = (nb + 6 < deg) ? bk[nb + 6] : make_uint2((unsigned)nn, 0u);

            // compute current batch (4 edges x 4 channels)
            {
                float m0 = (kb     < deg) ? 1.0f : 0.0f;
                float m1 = (kb + 2 < deg) ? 1.0f : 0.0f;
                float m2 = (kb + 4 < deg) ? 1.0f : 0.0f;
                float m3 = (kb + 6 < deg) ? 1.0f : 0.0f;

                float2 w0 = h2f(B0), w1 = h2f(B1), w2 = h2f(B2), w3 = h2f(B3);
                float2 l0 = h2f(X0.x), h0 = h2f(X0.y);
                float2 l1 = h2f(X1.x), h1 = h2f(X1.y);
                float2 l2 = h2f(X2.x), h2_ = h2f(X2.y);
                float2 l3 = h2f(X3.x), h3 = h2f(X3.y);

                float vdx, vdy, vdz, vdw;
                vdx = vi.x - l0.x; vdy = vi.y - l0.y; vdz = vi.z - h0.x; vdw = vi.w - h0.y;
                a0x += vdx * w0.x; a0y += vdy * w0.x; a0z += vdz * w0.x; a0w += vdw * w0.x;
                a1x += vdx * w0.y; a1y += vdy * w0.y; a1z += vdz * w0.y; a1w += vdw * w0.y;
                a2x += l0.x * m0;  a2y += l0.y * m0;  a2z += h0.x * m0;  a2w += h0.y * m0;

                vdx = vi.x - l1.x; vdy = vi.y - l1.y; vdz = vi.z - h1.x; vdw = vi.w - h1.y;
                a0x += vdx * w1.x; a0y += vdy * w1.x; a0z += vdz * w1.x; a0w += vdw * w1.x;
                a1x += vdx * w1.y; a1y += vdy * w1.y; a1z += vdz * w1.y; a1w += vdw * w1.y;
                a2x += l1.x * m1;  a2y += l1.y * m1;  a2z += h1.x * m1;  a2w += h1.y * m1;

                vdx = vi.x - l2.x; vdy = vi.y - l2.y; vdz = vi.z - h2_.x; vdw = vi.w - h2_.y;
                a0x += vdx * w2.x; a0y += vdy * w2.x; a0z += vdz * w2.x; a0w += vdw * w2.x;
                a1x += vdx * w2.y; a1y += vdy * w2.y; a1z += vdz * w2.y; a1w += vdw * w2.y;
                a2x += l2.x * m2;  a2y += l2.y * m2;  a2z += h2_.x * m2; a2w += h2_.y * m2;

                vdx = vi.x - l3.x; vdy = vi.y - l3.y; vdz = vi.z - h3.x; vdw = vi.w - h3.y;
                a0x += vdx * w3.x; a0y += vdy * w3.x; a0z += vdz * w3.x; a0w += vdw * w3.x;
                a1x += vdx * w3.y; a1y += vdy * w3.y; a1z += vdz * w3.y; a1w += vdw * w3.y;
                a2x += l3.x * m3;  a2y += l3.y * m3;  a2z += h3.x * m3;  a2w += h3.y * m3;
            }

            // issue next batch's x gathers (skip on last iteration)
            if (it + 1 < iters) {
                X0 = xh2[(size_t)F0.x * 8 + s];
                X1 = xh2[(size_t)F1.x * 8 + s];
                X2 = xh2[(size_t)F2.x * 8 + s];
                X3 = xh2[(size_t)F3.x * 8 + s];
                B0 = F0.y; B1 = F1.y; B2 = F2.y; B3 = F3.y;
            }
            kb = nb;
        }

        // combine edge halves (partner differs in bit 3 = g)
        a0x += __shfl_xor(a0x, 8); a0y += __shfl_xor(a0y, 8);
        a0z += __shfl_xor(a0z, 8); a0w += __shfl_xor(a0w, 8);
        a1x += __shfl_xor(a1x, 8); a1y += __shfl_xor(a1y, 8);
        a1z += __shfl_xor(a1z, 8); a1w += __shfl_xor(a1w, 8);
        a2x += __shfl_xor(a2x, 8); a2y += __shfl_xor(a2y, 8);
        a2z += __shfl_xor(a2z, 8); a2w += __shfl_xor(a2w, 8);

        float invd = 1.0f / fmaxf((float)cnt, 1.0f);
        if (g == 0) {
            prop4[wid][q][s]      = make_float4(a0x*invd, a0y*invd, a0z*invd, a0w*invd);
            prop4[wid][q][8 + s]  = make_float4(a1x*invd, a1y*invd, a1z*invd, a1w*invd);
            prop4[wid][q][16 + s] = make_float4(a2x*invd, a2y*invd, a2z*invd, a2w*invd);
            prop4[wid][q][24 + s] = vi;
        }
        // same-wave LDS RAW fence (prop is wave-private; no barrier needed)
        asm volatile("s_waitcnt lgkmcnt(0)" ::: "memory");

        // matvec: lane = oc, 4 nodes per W-read
        float bb = bs[oc];
        float acc0 = bb, acc1 = bb, acc2 = bb, acc3 = bb;
        #pragma unroll 8
        for (int k4 = 0; k4 < 32; ++k4) {
            float4 w   = Wt4[k4 * 64 + oc];
            float4 pp0 = prop4[wid][0][k4];
            float4 pp1 = prop4[wid][1][k4];
            float4 pp2 = prop4[wid][2][k4];
            float4 pp3 = prop4[wid][3][k4];
            acc0 += w.x*pp0.x + w.y*pp0.y + w.z*pp0.z + w.w*pp0.w;
            acc1 += w.x*pp1.x + w.y*pp1.y + w.z*pp1.z + w.w*pp1.w;
            acc2 += w.x*pp2.x + w.y*pp2.y + w.z*pp2.z + w.w*pp2.w;
            acc3 += w.x*pp3.x + w.y*pp3.y + w.z*pp3.z + w.w*pp3.w;
        }

        float accq[4] = {acc0, acc1, acc2, acc3};
        #pragma unroll
        for (int qq = 0; qq < 4; ++qq) {
            int n2 = wg * 4 + qq;
            if (n2 < NN) {
                float h = fmaxf(accq[qq], 0.0f);
                float2 pp = pos2[n2];
                int b = batch[n2];
                int vx = min(max((int)floorf(pp.x * 16.0f), 0), 15);
                int vy = min(max((int)floorf(pp.y * 16.0f), 0), 15);
                int cl = b * 256 + vy * 16 + vx;
                unsigned int* tgt = (unsigned int*)(out + (size_t)cl * 64 + oc);
                // monotonic-from-zero: stale read is a valid lower bound
                unsigned int prev = *tgt;
                unsigned int cur  = __float_as_uint(h);
                if (cur > prev) atomicMax(tgt, cur);
                if (oc == qq) {
                    *(float2*)(out + OUT_POS + 2 * (size_t)n2) = pp;
                    out[OUT_BATCH + n2] = (float)b;
                    atomicAdd(pos_sum + 2 * cl,     pp.x);
                    atomicAdd(pos_sum + 2 * cl + 1, pp.y);
                    atomicAdd(node_cnt + cl, 1.0f);
                }
            }
        }
        // WAR fence before next iteration overwrites prop
        asm volatile("s_waitcnt lgkmcnt(0)" ::: "memory");
    }
}

// ---------------------------------------------------------------------------
// K3: finalize pooled positions.
// ---------------------------------------------------------------------------
__global__ void finalize_kernel(const float* __restrict__ pos_sum,
                                const float* __restrict__ node_cnt,
                                float* __restrict__ out_pooled_pos)
{
    int c = blockIdx.x * blockDim.x + threadIdx.x;
    if (c >= NCLUST) return;
    float inv = 1.0f / fmaxf(node_cnt[c], 1.0f);
    out_pooled_pos[2 * c]     = pos_sum[2 * c] * inv;
    out_pooled_pos[2 * c + 1] = pos_sum[2 * c + 1] * inv;
}

extern "C" void kernel_launch(void* const* d_in, const int* in_sizes, int n_in,
                              void* d_out, int out_size, void* d_ws, size_t ws_size,
                              hipStream_t stream)
{
    const float* x     = (const float*)d_in[0];
    const int*   ei    = (const int*)d_in[1];
    const float* pos   = (const float*)d_in[2];
    const int*   batch = (const int*)d_in[3];
    const float* W     = (const float*)d_in[4];
    const float* bvec  = (const float*)d_in[5];
    float* out = (float*)d_out;

    // ws layout: wp[NN] int | csr64[NN*cap] uint2 | xh2[NN*8] uint2 | pos_sum | node_cnt
    size_t fixed = (size_t)NN * 4 + (size_t)NN * 8 * 8 + 3 * NCLUST * 4;
    int cap = 40;   // P(Poisson(16) > 40) ~ 1e-8
    if (ws_size < fixed + (size_t)NN * cap * 8) {
        cap = (int)((ws_size - fixed) / ((size_t)NN * 8));
        if (cap > 40) cap = 40;
    }

    int* wp = (int*)d_ws;
    uint2* csr64 = (uint2*)(wp + NN);
    uint2* xh2 = csr64 + (size_t)NN * cap;
    float* pos_sum  = (float*)(xh2 + (size_t)NN * 8);
    float* node_cnt = pos_sum + 2 * NCLUST;

    hipMemsetAsync(wp, 0, NN * sizeof(int), stream);
    hipMemsetAsync(pos_sum, 0, 3 * NCLUST * sizeof(float), stream);
    hipMemsetAsync(d_out, 0, (size_t)NCLUST * 64 * sizeof(float), stream);

    cvt_kernel<<<(NN * 8 + 255) / 256, 256, 0, stream>>>((const float4*)x, xh2);

    fill_kernel<<<(NE / 4 + 255) / 256, 256, 0, stream>>>(
        ei, (const float2*)pos, wp, csr64, cap);

    fused_kernel<<<512, 1024, 0, stream>>>(
        (const float4*)x, xh2, (const float2*)pos, batch,
        (const float4*)W, bvec, wp, csr64, cap, out, pos_sum, node_cnt);

    finalize_kernel<<<(NCLUST + 255) / 256, 256, 0, stream>>>(
        pos_sum, node_cnt, out + NCLUST * 64);
}

// Round 8
// 248.711 us; speedup vs baseline: 1.2860x; 1.0535x over previous
//
#include <hip/hip_runtime.h>
#include <hip/hip_fp16.h>

#define NN 100000
#define NE 1600000
#define NCLUST 1024
#define OUT_POOLED_POS 65536
#define OUT_POS        67584
#define OUT_BATCH      267584

static __device__ __forceinline__ float2 h2f(unsigned int u)
{
    __half2 h = *reinterpret_cast<__half2*>(&u);
    return __half22float2(h);
}

// ---------------------------------------------------------------------------
// K0: x -> fp16. Flat uint view: xh32[n*16 + m] = channels {2m, 2m+1}.
// ---------------------------------------------------------------------------
__global__ __launch_bounds__(256) void cvt_kernel(const float4* __restrict__ x4,
                                                  uint2* __restrict__ xh2)
{
    int t = blockIdx.x * 256 + threadIdx.x;
    if (t >= NN * 8) return;
    float4 v = x4[t];
    __half2 lo = __floats2half2_rn(v.x, v.y);
    __half2 hi = __floats2half2_rn(v.z, v.w);
    uint2 o;
    o.x = *reinterpret_cast<unsigned int*>(&lo);
    o.y = *reinterpret_cast<unsigned int*>(&hi);
    xh2[t] = o;
}

// ---------------------------------------------------------------------------
// K1: bucket-CSR fill with precomputed edge weights.
// entry = uint2{ j, fp16x2(wx, wy) } at csr64[col*cap + slot].
// ---------------------------------------------------------------------------
__global__ __launch_bounds__(256) void fill_kernel(const int* __restrict__ ei,
                                                   const float2* __restrict__ pos2,
                                                   int* __restrict__ wp,
                                                   uint2* __restrict__ csr64,
                                                   int cap)
{
    int t = blockIdx.x * 256 + threadIdx.x;
    int e0 = t * 4;
    if (e0 + 3 < NE) {
        int4 r = *(const int4*)(ei + e0);
        int4 c = *(const int4*)(ei + NE + e0);
        int rr[4] = {r.x, r.y, r.z, r.w};
        int cc[4] = {c.x, c.y, c.z, c.w};
        #pragma unroll
        for (int u = 0; u < 4; ++u) {
            int row = rr[u], col = cc[u];
            float2 pi = pos2[col], pj = pos2[row];
            float dx = pi.x - pj.x, dy = pi.y - pj.y;
            float inv = __builtin_amdgcn_rcpf(dx * dx + dy * dy + 0.01f);
            __half2 h2 = __floats2half2_rn(dx * inv, dy * inv);
            unsigned int wbits = *reinterpret_cast<unsigned int*>(&h2);
            int s = atomicAdd(&wp[col], 1);
            if (s < cap) csr64[(size_t)col * cap + s] = make_uint2((unsigned)row, wbits);
        }
    } else {
        for (int e = e0; e < NE; ++e) {
            int row = ei[e], col = ei[NE + e];
            float2 pi = pos2[col], pj = pos2[row];
            float dx = pi.x - pj.x, dy = pi.y - pj.y;
            float inv = __builtin_amdgcn_rcpf(dx * dx + dy * dy + 0.01f);
            __half2 h2 = __floats2half2_rn(dx * inv, dy * inv);
            unsigned int wbits = *reinterpret_cast<unsigned int*>(&h2);
            int s = atomicAdd(&wp[col], 1);
            if (s < cap) csr64[(size_t)col * cap + s] = make_uint2((unsigned)row, wbits);
        }
    }
}

// ---------------------------------------------------------------------------
// K2: fused gather + mean + linear + relu + voxel max-pool + pos epilogue.
// 512 blocks x 16 waves, per-wave grid-stride; waves independent in loop.
// Lane map: lane = q*16 + s  (q = node 0..3, s = channel-pair 0..15).
// Each lane owns 2 channels -> 6 f32 accumulators (was 12), batch-4
// pipeline state fits in the 64-VGPR budget of launch_bounds(1024,8):
// no spills, prefetches stay hoisted.
// Per step: 4 contiguous CSR entries + 4 random 4B fp16-pair gathers in
// flight while previous batch computes. No cross-lane combine needed.
// ---------------------------------------------------------------------------
__global__ __launch_bounds__(1024, 8) void fused_kernel(
    const float2* __restrict__ xf2,   // [NN*16] f32 channel pairs
    const unsigned int* __restrict__ xh32, // [NN*16] fp16 channel pairs
    const float2* __restrict__ pos2,
    const int* __restrict__ batch,
    const float4* __restrict__ W4,    // W[64][128] as float4
    const float* __restrict__ bv,
    const int* __restrict__ wp,
    const uint2* __restrict__ csr64,
    int cap,
    float* __restrict__ out,
    float* __restrict__ pos_sum,
    float* __restrict__ node_cnt)
{
    __shared__ float4 Wt4[32 * 64];      // [k4][oc]
    __shared__ float  bs[64];
    __shared__ float4 prop4[16][4][32];  // [wave][q][k4]

    {
        int oc0 = threadIdx.x & 63;
        int k0  = threadIdx.x >> 6;
        Wt4[k0 * 64 + oc0]        = W4[oc0 * 32 + k0];
        Wt4[(k0 + 16) * 64 + oc0] = W4[oc0 * 32 + k0 + 16];
        if (threadIdx.x < 64) bs[threadIdx.x] = bv[threadIdx.x];
    }
    __syncthreads();

    const int wid  = threadIdx.x >> 6;
    const int lane = threadIdx.x & 63;
    const int q  = lane >> 4;            // node within wave (lane bits 4-5)
    const int s  = lane & 15;            // channel pair
    const int oc = lane;
    const int nwaves = gridDim.x * 16;

    for (int wg = blockIdx.x * 16 + wid; wg * 4 < NN; wg += nwaves) {
        int n = wg * 4 + q;
        bool act = (n < NN);
        int nn = act ? n : 0;

        int cnt = wp[nn];
        int deg = act ? min(cnt, cap) : 0;
        float2 vi = xf2[(size_t)nn * 16 + s];
        const uint2* bk = csr64 + (size_t)nn * cap;

        // wave-uniform max degree (q = lane bits 4..5)
        int md = deg;
        md = max(md, __shfl_xor(md, 16));
        md = max(md, __shfl_xor(md, 32));

        float a0x = 0.f, a0y = 0.f;
        float a1x = 0.f, a1y = 0.f;
        float a2x = 0.f, a2y = 0.f;

        // batch-4 prologue (edges 0..3 of this node)
        uint2 E0 = (0 < deg) ? bk[0] : make_uint2((unsigned)nn, 0u);
        uint2 E1 = (1 < deg) ? bk[1] : make_uint2((unsigned)nn, 0u);
        uint2 E2 = (2 < deg) ? bk[2] : make_uint2((unsigned)nn, 0u);
        uint2 E3 = (3 < deg) ? bk[3] : make_uint2((unsigned)nn, 0u);
        unsigned int X0 = xh32[(size_t)E0.x * 16 + s];
        unsigned int X1 = xh32[(size_t)E1.x * 16 + s];
        unsigned int X2 = xh32[(size_t)E2.x * 16 + s];
        unsigned int X3 = xh32[(size_t)E3.x * 16 + s];
        unsigned int B0 = E0.y, B1 = E1.y, B2 = E2.y, B3 = E3.y;
        float m0 = (0 < deg) ? 1.f : 0.f;
        float m1 = (1 < deg) ? 1.f : 0.f;
        float m2 = (2 < deg) ? 1.f : 0.f;
        float m3 = (3 < deg) ? 1.f : 0.f;

        int kb = 0;
        int iters = (md + 3) >> 2;           // wave-uniform
        for (int it = 0; it < iters; ++it) {
            int nb = kb + 4;
            // next-batch entries (contiguous, cache-hot)
            uint2 F0 = (nb     < deg) ? bk[nb]     : make_uint2((unsigned)nn, 0u);
            uint2 F1 = (nb + 1 < deg) ? bk[nb + 1] : make_uint2((unsigned)nn, 0u);
            uint2 F2 = (nb + 2 < deg) ? bk[nb + 2] : make_uint2((unsigned)nn, 0u);
            uint2 F3 = (nb + 3 < deg) ? bk[nb + 3] : make_uint2((unsigned)nn, 0u);

            // compute current batch (4 edges x 2 channels)
            {
                float2 w0 = h2f(B0), w1 = h2f(B1), w2 = h2f(B2), w3 = h2f(B3);
                float2 v0 = h2f(X0), v1 = h2f(X1), v2 = h2f(X2), v3 = h2f(X3);
                float vdx, vdy;
                vdx = vi.x - v0.x; vdy = vi.y - v0.y;
                a0x += vdx * w0.x; a0y += vdy * w0.x;
                a1x += vdx * w0.y; a1y += vdy * w0.y;
                a2x += v0.x * m0;  a2y += v0.y * m0;

                vdx = vi.x - v1.x; vdy = vi.y - v1.y;
                a0x += vdx * w1.x; a0y += vdy * w1.x;
                a1x += vdx * w1.y; a1y += vdy * w1.y;
                a2x += v1.x * m1;  a2y += v1.y * m1;

                vdx = vi.x - v2.x; vdy = vi.y - v2.y;
                a0x += vdx * w2.x; a0y += vdy * w2.x;
                a1x += vdx * w2.y; a1y += vdy * w2.y;
                a2x += v2.x * m2;  a2y += v2.y * m2;

                vdx = vi.x - v3.x; vdy = vi.y - v3.y;
                a0x += vdx * w3.x; a0y += vdy * w3.x;
                a1x += vdx * w3.y; a1y += vdy * w3.y;
                a2x += v3.x * m3;  a2y += v3.y * m3;
            }

            // issue next batch's x gathers (skip on last iteration)
            if (it + 1 < iters) {
                X0 = xh32[(size_t)F0.x * 16 + s];
                X1 = xh32[(size_t)F1.x * 16 + s];
                X2 = xh32[(size_t)F2.x * 16 + s];
                X3 = xh32[(size_t)F3.x * 16 + s];
                B0 = F0.y; B1 = F1.y; B2 = F2.y; B3 = F3.y;
                m0 = (nb     < deg) ? 1.f : 0.f;
                m1 = (nb + 1 < deg) ? 1.f : 0.f;
                m2 = (nb + 2 < deg) ? 1.f : 0.f;
                m3 = (nb + 3 < deg) ? 1.f : 0.f;
            }
            kb = nb;
        }

        float invd = 1.0f / fmaxf((float)cnt, 1.0f);
        if (act) {
            float2* pw = (float2*)&prop4[wid][q][0];   // 64 float2 = 128 ch
            pw[s]      = make_float2(a0x * invd, a0y * invd);
            pw[16 + s] = make_float2(a1x * invd, a1y * invd);
            pw[32 + s] = make_float2(a2x * invd, a2y * invd);
            pw[48 + s] = vi;
        }
        // same-wave LDS RAW fence (prop is wave-private; no barrier needed)
        asm volatile("s_waitcnt lgkmcnt(0)" ::: "memory");

        // matvec: lane = oc, 4 nodes per W-read
        float bb = bs[oc];
        float acc0 = bb, acc1 = bb, acc2 = bb, acc3 = bb;
        #pragma unroll 8
        for (int k4 = 0; k4 < 32; ++k4) {
            float4 w   = Wt4[k4 * 64 + oc];
            float4 pp0 = prop4[wid][0][k4];
            float4 pp1 = prop4[wid][1][k4];
            float4 pp2 = prop4[wid][2][k4];
            float4 pp3 = prop4[wid][3][k4];
            acc0 += w.x*pp0.x + w.y*pp0.y + w.z*pp0.z + w.w*pp0.w;
            acc1 += w.x*pp1.x + w.y*pp1.y + w.z*pp1.z + w.w*pp1.w;
            acc2 += w.x*pp2.x + w.y*pp2.y + w.z*pp2.z + w.w*pp2.w;
            acc3 += w.x*pp3.x + w.y*pp3.y + w.z*pp3.z + w.w*pp3.w;
        }

        float accq[4] = {acc0, acc1, acc2, acc3};
        #pragma unroll
        for (int qq = 0; qq < 4; ++qq) {
            int n2 = wg * 4 + qq;
            if (n2 < NN) {
                float h = fmaxf(accq[qq], 0.0f);
                float2 pp = pos2[n2];
                int b = batch[n2];
                int vx = min(max((int)floorf(pp.x * 16.0f), 0), 15);
                int vy = min(max((int)floorf(pp.y * 16.0f), 0), 15);
                int cl = b * 256 + vy * 16 + vx;
                unsigned int* tgt = (unsigned int*)(out + (size_t)cl * 64 + oc);
                // monotonic-from-zero: stale read is a valid lower bound
                unsigned int prev = *tgt;
                unsigned int cur  = __float_as_uint(h);
                if (cur > prev) atomicMax(tgt, cur);
                if (oc == qq) {
                    *(float2*)(out + OUT_POS + 2 * (size_t)n2) = pp;
                    out[OUT_BATCH + n2] = (float)b;
                    atomicAdd(pos_sum + 2 * cl,     pp.x);
                    atomicAdd(pos_sum + 2 * cl + 1, pp.y);
                    atomicAdd(node_cnt + cl, 1.0f);
                }
            }
        }
        // WAR fence before next iteration overwrites prop
        asm volatile("s_waitcnt lgkmcnt(0)" ::: "memory");
    }
}

// ---------------------------------------------------------------------------
// K3: finalize pooled positions.
// ---------------------------------------------------------------------------
__global__ void finalize_kernel(const float* __restrict__ pos_sum,
                                const float* __restrict__ node_cnt,
                                float* __restrict__ out_pooled_pos)
{
    int c = blockIdx.x * blockDim.x + threadIdx.x;
    if (c >= NCLUST) return;
    float inv = 1.0f / fmaxf(node_cnt[c], 1.0f);
    out_pooled_pos[2 * c]     = pos_sum[2 * c] * inv;
    out_pooled_pos[2 * c + 1] = pos_sum[2 * c + 1] * inv;
}

extern "C" void kernel_launch(void* const* d_in, const int* in_sizes, int n_in,
                              void* d_out, int out_size, void* d_ws, size_t ws_size,
                              hipStream_t stream)
{
    const float* x     = (const float*)d_in[0];
    const int*   ei    = (const int*)d_in[1];
    const float* pos   = (const float*)d_in[2];
    const int*   batch = (const int*)d_in[3];
    const float* W     = (const float*)d_in[4];
    const float* bvec  = (const float*)d_in[5];
    float* out = (float*)d_out;

    // ws layout: wp[NN] int | csr64[NN*cap] uint2 | xh2[NN*8] uint2 | pos_sum | node_cnt
    size_t fixed = (size_t)NN * 4 + (size_t)NN * 8 * 8 + 3 * NCLUST * 4;
    int cap = 40;   // P(Poisson(16) > 40) ~ 1e-8
    if (ws_size < fixed + (size_t)NN * cap * 8) {
        cap = (int)((ws_size - fixed) / ((size_t)NN * 8));
        if (cap > 40) cap = 40;
    }

    int* wp = (int*)d_ws;
    uint2* csr64 = (uint2*)(wp + NN);
    uint2* xh2 = csr64 + (size_t)NN * cap;
    float* pos_sum  = (float*)(xh2 + (size_t)NN * 8);
    float* node_cnt = pos_sum + 2 * NCLUST;

    hipMemsetAsync(wp, 0, NN * sizeof(int), stream);
    hipMemsetAsync(pos_sum, 0, 3 * NCLUST * sizeof(float), stream);
    hipMemsetAsync(d_out, 0, (size_t)NCLUST * 64 * sizeof(float), stream);

    cvt_kernel<<<(NN * 8 + 255) / 256, 256, 0, stream>>>((const float4*)x, xh2);

    fill_kernel<<<(NE / 4 + 255) / 256, 256, 0, stream>>>(
        ei, (const float2*)pos, wp, csr64, cap);

    fused_kernel<<<512, 1024, 0, stream>>>(
        (const float2*)x, (const unsigned int*)xh2, (const float2*)pos, batch,
        (const float4*)W, bvec, wp, csr64, cap, out, pos_sum, node_cnt);

    finalize_kernel<<<(NCLUST + 255) / 256, 256, 0, stream>>>(
        pos_sum, node_cnt, out + NCLUST * 64);
}